// Round 2
// baseline (364.805 us; speedup 1.0000x reference)
//
#include <hip/hip_runtime.h>
#include <stdint.h>

typedef unsigned short ushort_t;
typedef __bf16 bf16x8 __attribute__((ext_vector_type(8)));
typedef float floatx4 __attribute__((ext_vector_type(4)));
typedef unsigned short ushort8 __attribute__((ext_vector_type(8)));

__device__ __forceinline__ ushort_t f2b(float f) {
  union { float f; unsigned u; } v; v.f = f;
  unsigned r = v.u + 0x7fffu + ((v.u >> 16) & 1u);  // RNE
  return (ushort_t)(r >> 16);
}
__device__ __forceinline__ ushort_t b2u(float f) {  // native hw cvt
  union { __bf16 b; ushort_t u; } v; v.b = (__bf16)f; return v.u;
}
__device__ __forceinline__ bf16x8 cvt8(const float* p) {
  floatx4 f0 = *(const floatx4*)p;
  floatx4 f1 = *(const floatx4*)(p + 4);
  union { bf16x8 v; __bf16 e[8]; } u;
#pragma unroll
  for (int j = 0; j < 4; ++j) u.e[j] = (__bf16)f0[j];
#pragma unroll
  for (int j = 0; j < 4; ++j) u.e[4 + j] = (__bf16)f1[j];
  return u.v;
}

// async global->LDS, 16 bytes per lane (wave-uniform LDS base + lane*16)
__device__ __forceinline__ void async16(const ushort_t* g, ushort_t* l) {
  __builtin_amdgcn_global_load_lds(
      (const __attribute__((address_space(1))) void*)g,
      (__attribute__((address_space(3))) void*)l, 16, 0, 0);
}

// -------- x f32 -> bf16, 8 elems/thread --------
__global__ __launch_bounds__(256) void cvt_x(const float* __restrict__ src,
                                             ushort_t* __restrict__ dst, int n8) {
  int i = blockIdx.x * 256 + threadIdx.x;
  if (i < n8) *(bf16x8*)&dst[(size_t)i * 8] = cvt8(src + (size_t)i * 8);
}

// -------- weight transpose + f32->bf16: src[R][Cc] f32 -> dst[Cc][R] bf16 ----
__global__ void transpose_k(const float* __restrict__ src,
                            ushort_t* __restrict__ dst, int R, int Cc) {
  int idx = blockIdx.x * 256 + threadIdx.x;
  if (idx < R * Cc) {
    int r = idx / Cc, c = idx % Cc;
    dst[(size_t)c * R + r] = f2b(src[idx]);
  }
}

// ===================== GEMM v3: 8-phase pipelined (T2+T3+T4+T5+T1) ==========
// C[M][N] = A[M][K] @ Bt[N][K]^T (+bias). A,Bt bf16. C f32 or bf16.
// BM=256, BN=128, BK=64. 512 threads = 8 waves (4M x 2N), per-wave 64x64.
// Triple-buffered LDS (A 3x32KB + B 3x16KB = 144KB dynamic): prefetch
// distance = 2 K-tiles -> counted vmcnt(6) at tile boundary, never 0 in
// steady state. 4 phases per K-tile, each:
//   {ds_read frag subtile || issue 1-2 global_load_lds for tile kt+2}
//   s_barrier; setprio(1); 8 MFMA; setprio(0); [p==3: vmcnt(6)]; s_barrier
// Buffer safety: chunk for tile kt+2 overwrites buffer (kt+2)%3 == (kt-1)%3,
// whose last ds_reads completed before tile kt-1's final barrier (all waves
// joined) -> no overwrite race. Loads for tile T issued during kt=T-2, landed
// check at kt=T-1's boundary vmcnt before first read at kt=T.
template <int C_F32>
__global__ __launch_bounds__(512, 1) void gemm_p8(
    const ushort_t* __restrict__ A, int lda,
    const ushort_t* __restrict__ Bt,
    const float* __restrict__ bias, void* __restrict__ C_,
    int M, int N, int K) {
  extern __shared__ __align__(16) ushort_t lds[];
  ushort_t* ldsA = lds;                // 3 * 16384 elems
  ushort_t* ldsB = lds + 3 * 16384;    // 3 * 8192 elems
  const int t = threadIdx.x;

  // XCD-aware bijective swizzle (nwg % 8 == 0 by launch config)
  const int nwg = gridDim.x;
  const int per = nwg >> 3;
  const int swz = (blockIdx.x & 7) * per + (blockIdx.x >> 3);
  const int ntn = N >> 7;                 // n-tiles (BN=128)
  const int m0 = (swz / ntn) << 8;        // BM=256
  const int n0 = (swz % ntn) << 7;

  const int w = t >> 6, lane = t & 63;
  const int wm = w >> 1, wn = w & 1;      // 4M x 2N wave grid
  const int l15 = lane & 15, quad = lane >> 4;
  const int quad4 = quad << 2;

  floatx4 acc[4][4] = {};

  // staging: thread t covers row chunkbase + (t>>3), 16B chunk (t&7);
  // global source chunk pre-swizzled by ^(row&7) (both-sides swizzle rule).
  const int srow = t >> 3;                       // 0..63
  const int sc = (((t & 7) ^ (srow & 7)) << 3);  // swizzled col offset (elems)
  const int dLds = srow * 64 + (t & 7) * 8;      // linear LDS dest within chunk
  const ushort_t* gA = A + (size_t)(m0 + srow) * lda + sc;
  const ushort_t* gB = Bt + (size_t)(n0 + srow) * K + sc;

  auto stageA = [&](int buf, int c, int kofs) {
    async16(gA + (size_t)(c * 64) * lda + kofs,
            &ldsA[buf * 16384 + c * 4096 + dLds]);
  };
  auto stageB = [&](int buf, int c, int kofs) {
    async16(gB + (size_t)(c * 64) * K + kofs,
            &ldsB[buf * 8192 + c * 4096 + dLds]);
  };
  auto stage_tile = [&](int tile) {
    const int buf = tile % 3, kofs = tile << 6;
    stageA(buf, 0, kofs); stageA(buf, 1, kofs);
    stageA(buf, 2, kofs); stageA(buf, 3, kofs);
    stageB(buf, 0, kofs); stageB(buf, 1, kofs);
  };

  const int NT = K >> 6;  // 6 for K=384
  // prologue: tiles 0,1 staged (12 loads); wait tile 0 (6 still in flight)
  stage_tile(0);
  stage_tile(1);
  asm volatile("s_waitcnt vmcnt(6)" ::: "memory");
  __builtin_amdgcn_s_barrier();

  for (int kt = 0; kt < NT; ++kt) {
    const int buf = kt % 3;
    const ushort_t* Ab = &ldsA[buf * 16384];
    const ushort_t* Bb = &ldsB[buf * 8192];
    const int pt = kt + 2;
    const bool dopf = pt < NT;
    const int pbuf = pt % 3;
    const int pk = pt << 6;

    bf16x8 afc[2][2];  // A-frags cached across the qj pair of phases
#pragma unroll
    for (int p = 0; p < 4; ++p) {
      const int qi = p >> 1, qj = p & 1;
      if (qj == 0) {
#pragma unroll
        for (int ii = 0; ii < 2; ++ii) {
          const int row = wm * 64 + (qi * 2 + ii) * 16 + l15;
#pragma unroll
          for (int kk = 0; kk < 2; ++kk)
            afc[ii][kk] = *(const bf16x8*)&Ab[row * 64 +
                ((((kk << 2) | quad) ^ (row & 7)) << 3)];
        }
      }
      bf16x8 bfr[2][2];
#pragma unroll
      for (int jj = 0; jj < 2; ++jj) {
        const int row = wn * 64 + (qj * 2 + jj) * 16 + l15;
#pragma unroll
        for (int kk = 0; kk < 2; ++kk)
          bfr[jj][kk] = *(const bf16x8*)&Bb[row * 64 +
              ((((kk << 2) | quad) ^ (row & 7)) << 3)];
      }
      if (dopf) {
        if (p == 0)      { stageA(pbuf, 0, pk); stageA(pbuf, 1, pk); }
        else if (p == 1) { stageA(pbuf, 2, pk); stageA(pbuf, 3, pk); }
        else if (p == 2) { stageB(pbuf, 0, pk); }
        else             { stageB(pbuf, 1, pk); }
      }
      __builtin_amdgcn_s_barrier();
      __builtin_amdgcn_s_setprio(1);
#pragma unroll
      for (int ii = 0; ii < 2; ++ii)
#pragma unroll
        for (int jj = 0; jj < 2; ++jj)
#pragma unroll
          for (int kk = 0; kk < 2; ++kk)
            acc[qi * 2 + ii][qj * 2 + jj] =
                __builtin_amdgcn_mfma_f32_16x16x32_bf16(
                    afc[ii][kk], bfr[jj][kk], acc[qi * 2 + ii][qj * 2 + jj],
                    0, 0, 0);
      __builtin_amdgcn_s_setprio(0);
      if (p == 3 && kt < NT - 1) {
        if (dopf) asm volatile("s_waitcnt vmcnt(6)" ::: "memory");
        else      asm volatile("s_waitcnt vmcnt(0)" ::: "memory");
      }
      __builtin_amdgcn_s_barrier();
    }
  }

  float bv[4] = {0.f, 0.f, 0.f, 0.f};
  if (bias != nullptr) {
#pragma unroll
    for (int j = 0; j < 4; ++j) bv[j] = bias[n0 + wn * 64 + j * 16 + l15];
  }
#pragma unroll
  for (int i = 0; i < 4; ++i) {
#pragma unroll
    for (int r = 0; r < 4; ++r) {
      size_t row = (size_t)(m0 + wm * 64 + i * 16 + quad4 + r);
      if (C_F32) {
        float* cp = (float*)C_ + row * N + (n0 + wn * 64 + l15);
#pragma unroll
        for (int j = 0; j < 4; ++j) cp[j * 16] = acc[i][j][r] + bv[j];
      } else {
        ushort_t* cp = (ushort_t*)C_ + row * N + (n0 + wn * 64 + l15);
#pragma unroll
        for (int j = 0; j < 4; ++j) cp[j * 16] = f2b(acc[i][j][r] + bv[j]);
      }
    }
  }
}

// ===================== GEMM v2 (fallback, verified): m97 structure ==========
template <int C_F32>
__global__ __launch_bounds__(256) void gemm_bt(
    const ushort_t* __restrict__ A, int lda,
    const ushort_t* __restrict__ Bt,
    const float* __restrict__ bias, void* __restrict__ C_,
    int M, int N, int K) {
  __shared__ __align__(16) ushort_t As[128 * 64];
  __shared__ __align__(16) ushort_t Bs[128 * 64];
  const int t = threadIdx.x;
  const int nwg = gridDim.x;
  const int per = nwg >> 3;
  const int swz = (blockIdx.x & 7) * per + (blockIdx.x >> 3);
  const int ntn = N >> 7;
  const int m0 = (swz / ntn) << 7;
  const int n0 = (swz % ntn) << 7;
  const int w = t >> 6, lane = t & 63;
  const int wy = (w >> 1) << 6;
  const int wx = (w & 1) << 6;
  const int l15 = lane & 15;
  const int quad = lane >> 4;
  const int quad4 = quad << 2;
  floatx4 acc[4][4] = {};
  const int srow = t >> 3;
  const int sc = (((t & 7) ^ (srow & 7)) << 3);
  const ushort_t* gA = A + (size_t)(m0 + srow) * lda + sc;
  const ushort_t* gB = Bt + (size_t)(n0 + srow) * K + sc;
  for (int k0 = 0; k0 < K; k0 += 64) {
    __syncthreads();
#pragma unroll
    for (int r4 = 0; r4 < 4; ++r4) {
      async16(gA + (size_t)r4 * 32 * lda + k0, &As[r4 * 2048 + t * 8]);
      async16(gB + (size_t)r4 * 32 * K + k0, &Bs[r4 * 2048 + t * 8]);
    }
    __syncthreads();
#pragma unroll
    for (int kk = 0; kk < 2; ++kk) {
      bf16x8 af[4], bfr[4];
#pragma unroll
      for (int i = 0; i < 4; ++i) {
        int row = wy + i * 16 + l15;
        af[i] = *(const bf16x8*)&As[row * 64 + ((((kk << 2) | quad) ^ (row & 7)) << 3)];
      }
#pragma unroll
      for (int j = 0; j < 4; ++j) {
        int row = wx + j * 16 + l15;
        bfr[j] = *(const bf16x8*)&Bs[row * 64 + ((((kk << 2) | quad) ^ (row & 7)) << 3)];
      }
#pragma unroll
      for (int i = 0; i < 4; ++i)
#pragma unroll
        for (int j = 0; j < 4; ++j)
          acc[i][j] = __builtin_amdgcn_mfma_f32_16x16x32_bf16(
              af[i], bfr[j], acc[i][j], 0, 0, 0);
    }
  }
  float bv[4] = {0.f, 0.f, 0.f, 0.f};
  if (bias != nullptr) {
#pragma unroll
    for (int j = 0; j < 4; ++j) bv[j] = bias[n0 + wx + j * 16 + l15];
  }
#pragma unroll
  for (int i = 0; i < 4; ++i) {
#pragma unroll
    for (int r = 0; r < 4; ++r) {
      size_t row = (size_t)(m0 + wy + i * 16 + quad4 + r);
      if (C_F32) {
        float* cp = (float*)C_ + row * N + (n0 + wx + l15);
#pragma unroll
        for (int j = 0; j < 4; ++j) cp[j * 16] = acc[i][j][r] + bv[j];
      } else {
        ushort_t* cp = (ushort_t*)C_ + row * N + (n0 + wx + l15);
#pragma unroll
        for (int j = 0; j < 4; ++j) cp[j * 16] = f2b(acc[i][j][r] + bv[j]);
      }
    }
  }
}

// -------- window attention v2 over bf16 QKV buffer --------
__global__ __launch_bounds__(256, 2) void win_attn(
    const ushort_t* __restrict__ QKV, ushort_t* __restrict__ O, int ostride) {
  __shared__ __align__(16) ushort_t Plds[4][64 * 40];  // [query][32 keys + pad]
  __shared__ __align__(16) ushort_t Vt[4][32 * 72];    // [d][64 tokens + pad]
  const int blk = blockIdx.x;
  const int b = blk >> 6, g = blk & 63;
  const int gy = g >> 3, gx = g & 7;
  const int t = threadIdx.x, w = t >> 6, lane = t & 63;
  const int l15 = lane & 15, quad = lane >> 4;
  const int q8 = quad << 3, quad4 = quad << 2;
  const size_t bbase = (size_t)b * 4096 + (size_t)(gy * 8) * 64 + gx * 8;
  const float scale = 0.17677669529663687f;  // 1/sqrt(32)

  bf16x8 ones;
  {
    union { bf16x8 v; __bf16 e[8]; } u;
#pragma unroll
    for (int j = 0; j < 8; ++j) u.e[j] = (__bf16)1.0f;
    ones = u.v;
  }

  for (int hi = 0; hi < 3; ++hi) {
    const int h = w * 3 + hi;
    const size_t hq = (size_t)h * 32;

    {
      size_t row = bbase + (size_t)(lane >> 3) * 64 + (lane & 7);
      const ushort_t* vp = QKV + row * 1152 + 768 + hq;
#pragma unroll
      for (int i = 0; i < 4; ++i) {
        ushort8 vv = *(const ushort8*)(vp + i * 8);
#pragma unroll
        for (int j = 0; j < 8; ++j) Vt[w][(i * 8 + j) * 72 + lane] = vv[j];
      }
    }

    bf16x8 qf[4], kf[4];
#pragma unroll
    for (int i = 0; i < 4; ++i) {
      int tok = i * 16 + l15;
      size_t row = bbase + (size_t)(tok >> 3) * 64 + (tok & 7);
      qf[i] = *(const bf16x8*)(QKV + row * 1152 + hq + q8);
      kf[i] = *(const bf16x8*)(QKV + row * 1152 + 384 + hq + q8);
    }

    floatx4 s[4][4] = {};
#pragma unroll
    for (int i = 0; i < 4; ++i)
#pragma unroll
      for (int j = 0; j < 4; ++j)
        s[i][j] = __builtin_amdgcn_mfma_f32_16x16x32_bf16(
            qf[i], kf[j], s[i][j], 0, 0, 0);

    floatx4 o[4][2] = {};
    floatx4 osum[4] = {};
#pragma unroll
    for (int ks = 0; ks < 2; ++ks) {
#pragma unroll
      for (int i = 0; i < 4; ++i) {
#pragma unroll
        for (int r = 0; r < 4; ++r) {
          float p0 = __expf(s[i][2 * ks][r] * scale);
          float p1 = __expf(s[i][2 * ks + 1][r] * scale);
          int pr = (i * 16 + quad4 + r) * 40 + l15;
          Plds[w][pr] = b2u(p0);
          Plds[w][pr + 16] = b2u(p1);
        }
      }
      bf16x8 pf[4], vf[2];
#pragma unroll
      for (int i = 0; i < 4; ++i)
        pf[i] = *(const bf16x8*)&Plds[w][(i * 16 + l15) * 40 + q8];
#pragma unroll
      for (int j = 0; j < 2; ++j)
        vf[j] = *(const bf16x8*)&Vt[w][(j * 16 + l15) * 72 + ks * 32 + q8];
#pragma unroll
      for (int i = 0; i < 4; ++i) {
#pragma unroll
        for (int j = 0; j < 2; ++j)
          o[i][j] = __builtin_amdgcn_mfma_f32_16x16x32_bf16(
              pf[i], vf[j], o[i][j], 0, 0, 0);
        osum[i] = __builtin_amdgcn_mfma_f32_16x16x32_bf16(
            pf[i], ones, osum[i], 0, 0, 0);
      }
    }

#pragma unroll
    for (int i = 0; i < 4; ++i) {
#pragma unroll
      for (int r = 0; r < 4; ++r) {
        int tok = i * 16 + quad4 + r;
        size_t row = bbase + (size_t)(tok >> 3) * 64 + (tok & 7);
        float inv = 1.0f / osum[i][r];
        ushort_t* op = O + row * (size_t)ostride + hq;
#pragma unroll
        for (int j = 0; j < 2; ++j) op[j * 16 + l15] = b2u(o[i][j][r] * inv);
      }
    }
  }
}

extern "C" void kernel_launch(void* const* d_in, const int* in_sizes, int n_in,
                              void* d_out, int out_size, void* d_ws, size_t ws_size,
                              hipStream_t stream) {
  const float* x      = (const float*)d_in[0];  // [65536][384] f32
  const float* qkv_w  = (const float*)d_in[1];  // [384][1152] f32
  const float* proj_w = (const float*)d_in[2];  // [384][384] f32
  const float* proj_b = (const float*)d_in[3];  // [384] f32
  float* out = (float*)d_out;                   // [65536][384] f32

  const int M = 16 * 4096;  // 65536 tokens
  const size_t need =
      ((size_t)M * 1152 + (size_t)M * 384 + 1152 * 384 + 384 * 384) * 2;
  if (ws_size < need) return;

  ushort_t* qkv    = (ushort_t*)d_ws;
  ushort_t* xb     = qkv + (size_t)M * 1152;
  ushort_t* qkvwT  = xb + (size_t)M * 384;
  ushort_t* projwT = qkvwT + (size_t)1152 * 384;

  // one-time: allow 144KB dynamic LDS for the 8-phase gemm
  static bool p8init = false, p8ok = false;
  if (!p8init) {
    p8ok = (hipFuncSetAttribute(
                reinterpret_cast<const void*>(gemm_p8<0>),
                hipFuncAttributeMaxDynamicSharedMemorySize, 147456) == hipSuccess) &&
           (hipFuncSetAttribute(
                reinterpret_cast<const void*>(gemm_p8<1>),
                hipFuncAttributeMaxDynamicSharedMemorySize, 147456) == hipSuccess);
    p8init = true;
  }

  cvt_x<<<(M * 384 / 8 + 255) / 256, 256, 0, stream>>>(x, xb, M * 384 / 8);
  transpose_k<<<(384 * 1152 + 255) / 256, 256, 0, stream>>>(qkv_w, qkvwT, 384, 1152);
  transpose_k<<<(384 * 384 + 255) / 256, 256, 0, stream>>>(proj_w, projwT, 384, 384);

  if (p8ok) {
    gemm_p8<0><<<(M / 256) * (1152 / 128), 512, 147456, stream>>>(
        xb, 384, qkvwT, nullptr, qkv, M, 1152, 384);
  } else {
    gemm_bt<0><<<(M / 128) * (1152 / 128), 256, 0, stream>>>(
        xb, 384, qkvwT, nullptr, qkv, M, 1152, 384);
  }

  win_attn<<<16 * 64, 256, 0, stream>>>(qkv, qkv, 1152);

  if (p8ok) {
    gemm_p8<1><<<(M / 256) * (384 / 128), 512, 147456, stream>>>(
        qkv, 1152, projwT, proj_b, out, M, 384, 384);
  } else {
    gemm_bt<1><<<(M / 128) * (384 / 128), 256, 0, stream>>>(
        qkv, 1152, projwT, proj_b, out, M, 384, 384);
  }
}

// Round 3
// 342.089 us; speedup vs baseline: 1.0664x; 1.0664x over previous
//
#include <hip/hip_runtime.h>
#include <stdint.h>

typedef unsigned short ushort_t;
typedef __bf16 bf16x8 __attribute__((ext_vector_type(8)));
typedef float floatx4 __attribute__((ext_vector_type(4)));
typedef float floatx16 __attribute__((ext_vector_type(16)));
typedef unsigned short ushort8 __attribute__((ext_vector_type(8)));

__device__ __forceinline__ ushort_t f2b(float f) {
  union { float f; unsigned u; } v; v.f = f;
  unsigned r = v.u + 0x7fffu + ((v.u >> 16) & 1u);  // RNE
  return (ushort_t)(r >> 16);
}
__device__ __forceinline__ ushort_t b2u(float f) {  // native hw cvt
  union { __bf16 b; ushort_t u; } v; v.b = (__bf16)f; return v.u;
}
__device__ __forceinline__ bf16x8 cvt8(const float* p) {
  floatx4 f0 = *(const floatx4*)p;
  floatx4 f1 = *(const floatx4*)(p + 4);
  union { bf16x8 v; __bf16 e[8]; } u;
#pragma unroll
  for (int j = 0; j < 4; ++j) u.e[j] = (__bf16)f0[j];
#pragma unroll
  for (int j = 0; j < 4; ++j) u.e[4 + j] = (__bf16)f1[j];
  return u.v;
}

// pack two f32 -> one dword of two bf16 (lo = a, hi = b), RNE hw cvt
__device__ __forceinline__ unsigned cvtpk(float a, float b) {
  unsigned r;
  asm("v_cvt_pk_bf16_f32 %0, %1, %2" : "=v"(r) : "v"(a), "v"(b));
  return r;
}
// exchange x.lanes[32..63] <-> y.lanes[0..31]
__device__ __forceinline__ void plswap(unsigned& x, unsigned& y) {
  asm("v_permlane32_swap_b32 %0, %1" : "+v"(x), "+v"(y));
}

// async global->LDS, 16 bytes per lane (wave-uniform LDS base + lane*16)
__device__ __forceinline__ void async16(const ushort_t* g, ushort_t* l) {
  __builtin_amdgcn_global_load_lds(
      (const __attribute__((address_space(1))) void*)g,
      (__attribute__((address_space(3))) void*)l, 16, 0, 0);
}

// -------- x f32 -> bf16, 8 elems/thread --------
__global__ __launch_bounds__(256) void cvt_x(const float* __restrict__ src,
                                             ushort_t* __restrict__ dst, int n8) {
  int i = blockIdx.x * 256 + threadIdx.x;
  if (i < n8) *(bf16x8*)&dst[(size_t)i * 8] = cvt8(src + (size_t)i * 8);
}

// -------- weight transpose + f32->bf16: src[R][Cc] f32 -> dst[Cc][R] bf16 ----
__global__ void transpose_k(const float* __restrict__ src,
                            ushort_t* __restrict__ dst, int R, int Cc) {
  int idx = blockIdx.x * 256 + threadIdx.x;
  if (idx < R * Cc) {
    int r = idx / Cc, c = idx % Cc;
    dst[(size_t)c * R + r] = f2b(src[idx]);
  }
}

// -------- GEMM (round-1 verified): C[M][N] = A[M][K] @ Bt[N][K]^T (+bias) ----
// 128x128 tile, 4 waves, BK=64, XOR-swizzled LDS (both-sides), XCD swizzle.
template <int C_F32>
__global__ __launch_bounds__(256) void gemm_bt(
    const ushort_t* __restrict__ A, int lda,
    const ushort_t* __restrict__ Bt,
    const float* __restrict__ bias, void* __restrict__ C_,
    int M, int N, int K) {
  __shared__ __align__(16) ushort_t As[128 * 64];
  __shared__ __align__(16) ushort_t Bs[128 * 64];
  const int t = threadIdx.x;
  const int nwg = gridDim.x;
  const int per = nwg >> 3;
  const int swz = (blockIdx.x & 7) * per + (blockIdx.x >> 3);
  const int ntn = N >> 7;
  const int m0 = (swz / ntn) << 7;
  const int n0 = (swz % ntn) << 7;
  const int w = t >> 6, lane = t & 63;
  const int wy = (w >> 1) << 6;
  const int wx = (w & 1) << 6;
  const int l15 = lane & 15;
  const int quad = lane >> 4;
  const int quad4 = quad << 2;
  floatx4 acc[4][4] = {};
  const int srow = t >> 3;
  const int sc = (((t & 7) ^ (srow & 7)) << 3);
  const ushort_t* gA = A + (size_t)(m0 + srow) * lda + sc;
  const ushort_t* gB = Bt + (size_t)(n0 + srow) * K + sc;
  for (int k0 = 0; k0 < K; k0 += 64) {
    __syncthreads();
#pragma unroll
    for (int r4 = 0; r4 < 4; ++r4) {
      async16(gA + (size_t)r4 * 32 * lda + k0, &As[r4 * 2048 + t * 8]);
      async16(gB + (size_t)r4 * 32 * K + k0, &Bs[r4 * 2048 + t * 8]);
    }
    __syncthreads();
#pragma unroll
    for (int kk = 0; kk < 2; ++kk) {
      bf16x8 af[4], bfr[4];
#pragma unroll
      for (int i = 0; i < 4; ++i) {
        int row = wy + i * 16 + l15;
        af[i] = *(const bf16x8*)&As[row * 64 + ((((kk << 2) | quad) ^ (row & 7)) << 3)];
      }
#pragma unroll
      for (int j = 0; j < 4; ++j) {
        int row = wx + j * 16 + l15;
        bfr[j] = *(const bf16x8*)&Bs[row * 64 + ((((kk << 2) | quad) ^ (row & 7)) << 3)];
      }
#pragma unroll
      for (int i = 0; i < 4; ++i)
#pragma unroll
        for (int j = 0; j < 4; ++j)
          acc[i][j] = __builtin_amdgcn_mfma_f32_16x16x32_bf16(
              af[i], bfr[j], acc[i][j], 0, 0, 0);
    }
  }
  float bv[4] = {0.f, 0.f, 0.f, 0.f};
  if (bias != nullptr) {
#pragma unroll
    for (int j = 0; j < 4; ++j) bv[j] = bias[n0 + wx + j * 16 + l15];
  }
#pragma unroll
  for (int i = 0; i < 4; ++i) {
#pragma unroll
    for (int r = 0; r < 4; ++r) {
      size_t row = (size_t)(m0 + wy + i * 16 + quad4 + r);
      if (C_F32) {
        float* cp = (float*)C_ + row * N + (n0 + wx + l15);
#pragma unroll
        for (int j = 0; j < 4; ++j) cp[j * 16] = acc[i][j][r] + bv[j];
      } else {
        ushort_t* cp = (ushort_t*)C_ + row * N + (n0 + wx + l15);
#pragma unroll
        for (int j = 0; j < 4; ++j) cp[j * 16] = f2b(acc[i][j][r] + bv[j]);
      }
    }
  }
}

// -------- window attention v3: 32x32 MFMA, swapped QK^T, in-register P ------
// QKV: [B*4096][1152] bf16, col = c3*384 + h*32 + d. O aliases Q region.
// 1 block per (b,window); wave w handles heads w*3..w*3+2. No barriers.
// v3: S^T = mfma_32x32x16(K, Q) -> lane holds S[q=lane&31][k by reg]. Row-sum
// is lane-local (+1 shfl_xor(32)); P normalized in f32, packed to bf16 via
// v_cvt_pk_bf16_f32 and redistributed with v_permlane32_swap_b32 (2 swaps per
// A-frag) -> NO P LDS roundtrip. Only V^T staged in LDS (18.4 KB/block).
__global__ __launch_bounds__(256, 2) void win_attn(
    const ushort_t* __restrict__ QKV, ushort_t* __restrict__ O, int ostride) {
  __shared__ __align__(16) ushort_t Vt[4][32 * 72];  // [d][64 tokens + pad]
  const int blk = blockIdx.x;
  const int b = blk >> 6, g = blk & 63;
  const int gy = g >> 3, gx = g & 7;
  const int t = threadIdx.x, w = t >> 6, lane = t & 63;
  const int l31 = lane & 31, bh = lane >> 5;
  // token tok (0..63, iy-major) -> global row = bbase + (tok>>3)*64 + (tok&7)
  const size_t bbase = (size_t)b * 4096 + (size_t)(gy * 8) * 64 + gx * 8;
  const float scale = 0.17677669529663687f;  // 1/sqrt(32)

  for (int hi = 0; hi < 3; ++hi) {
    const int h = w * 3 + hi;
    const size_t hq = (size_t)h * 32;

    // stage V^T into per-wave LDS: Vt[d][tok], stride 72 (2-way/free banks)
    {
      size_t row = bbase + (size_t)(lane >> 3) * 64 + (lane & 7);
      const ushort_t* vp = QKV + row * 1152 + 768 + hq;
#pragma unroll
      for (int i = 0; i < 4; ++i) {
        ushort8 vv = *(const ushort8*)(vp + i * 8);
#pragma unroll
        for (int j = 0; j < 8; ++j) Vt[w][(i * 8 + j) * 72 + lane] = vv[j];
      }
    }

    // Q B-frags (persist): Q[q = qt*32+l31][d = dc*16 + bh*8 .. +7]
    bf16x8 qf[2][2];
#pragma unroll
    for (int qt = 0; qt < 2; ++qt) {
      int tok = qt * 32 + l31;
      size_t row = bbase + (size_t)(tok >> 3) * 64 + (tok & 7);
#pragma unroll
      for (int dc = 0; dc < 2; ++dc)
        qf[qt][dc] = *(const bf16x8*)(QKV + row * 1152 + hq + dc * 16 + bh * 8);
    }

    // S^T = K Q^T via mfma(A=K-rows, B=Q-rows):
    // st[kt][qt] lane holds S[q = qt*32+lane&31][k = kt*32 + (reg&3)+8*(reg>>2)+4*bh]
    floatx16 st[2][2] = {};
#pragma unroll
    for (int kt = 0; kt < 2; ++kt) {
      bf16x8 kf[2];
      int tok = kt * 32 + l31;
      size_t row = bbase + (size_t)(tok >> 3) * 64 + (tok & 7);
#pragma unroll
      for (int dc = 0; dc < 2; ++dc)
        kf[dc] = *(const bf16x8*)(QKV + row * 1152 + 384 + hq + dc * 16 + bh * 8);
#pragma unroll
      for (int qt = 0; qt < 2; ++qt)
#pragma unroll
        for (int dc = 0; dc < 2; ++dc)
          st[kt][qt] = __builtin_amdgcn_mfma_f32_32x32x16_bf16(
              kf[dc], qf[qt][dc], st[kt][qt], 0, 0, 0);
    }

    // softmax: p = exp(s*scale) (scores ~N(0,1), no max-sub needed);
    // lane-local partial rowsum + one cross-half exchange
    float rs[2] = {0.f, 0.f};
#pragma unroll
    for (int kt = 0; kt < 2; ++kt)
#pragma unroll
      for (int qt = 0; qt < 2; ++qt)
#pragma unroll
        for (int r = 0; r < 16; ++r) {
          float e = __expf(st[kt][qt][r] * scale);
          st[kt][qt][r] = e;
          rs[qt] += e;
        }
#pragma unroll
    for (int qt = 0; qt < 2; ++qt) rs[qt] += __shfl_xor(rs[qt], 32);
    float inv[2] = {1.0f / rs[0], 1.0f / rs[1]};

    // PV: assemble normalized-P A-frags in-register (cvt_pk + permlane swaps)
    floatx16 o[2] = {};
#pragma unroll
    for (int s = 0; s < 4; ++s) {
      const int kt = s >> 1, r1x = (s & 1) << 1;  // reg groups 4*r1x.. / +4..
      bf16x8 vf = *(const bf16x8*)&Vt[w][l31 * 72 + s * 16 + bh * 8];
#pragma unroll
      for (int qt = 0; qt < 2; ++qt) {
        float iv = inv[qt];
        unsigned x0 = cvtpk(st[kt][qt][4 * r1x + 0] * iv, st[kt][qt][4 * r1x + 1] * iv);
        unsigned x1 = cvtpk(st[kt][qt][4 * r1x + 2] * iv, st[kt][qt][4 * r1x + 3] * iv);
        unsigned y0 = cvtpk(st[kt][qt][4 * r1x + 4] * iv, st[kt][qt][4 * r1x + 5] * iv);
        unsigned y1 = cvtpk(st[kt][qt][4 * r1x + 6] * iv, st[kt][qt][4 * r1x + 7] * iv);
        plswap(x0, y0);  // x0 -> frag dw0, y0 -> frag dw2
        plswap(x1, y1);  // x1 -> frag dw1, y1 -> frag dw3
        union { unsigned d[4]; bf16x8 v; } pa;
        pa.d[0] = x0; pa.d[1] = x1; pa.d[2] = y0; pa.d[3] = y1;
        o[qt] = __builtin_amdgcn_mfma_f32_32x32x16_bf16(pa.v, vf, o[qt], 0, 0, 0);
      }
    }

    // store merged-head output: o[qt][reg] = O[qt*32+(reg&3)+8*(reg>>2)+4*bh][l31]
#pragma unroll
    for (int qt = 0; qt < 2; ++qt)
#pragma unroll
      for (int r = 0; r < 16; ++r) {
        int tok = qt * 32 + (r & 3) + 8 * (r >> 2) + 4 * bh;
        size_t row = bbase + (size_t)(tok >> 3) * 64 + (tok & 7);
        O[row * (size_t)ostride + hq + l31] = b2u(o[qt][r]);
      }
  }
}

extern "C" void kernel_launch(void* const* d_in, const int* in_sizes, int n_in,
                              void* d_out, int out_size, void* d_ws, size_t ws_size,
                              hipStream_t stream) {
  const float* x      = (const float*)d_in[0];  // [65536][384] f32
  const float* qkv_w  = (const float*)d_in[1];  // [384][1152] f32
  const float* proj_w = (const float*)d_in[2];  // [384][384] f32
  const float* proj_b = (const float*)d_in[3];  // [384] f32
  float* out = (float*)d_out;                   // [65536][384] f32

  const int M = 16 * 4096;  // 65536 tokens
  const size_t need =
      ((size_t)M * 1152 + (size_t)M * 384 + 1152 * 384 + 384 * 384) * 2;
  if (ws_size < need) return;  // diagnostic: finite absmax => ws too small

  ushort_t* qkv    = (ushort_t*)d_ws;                 // M*1152 bf16 (Q region reused as attn out)
  ushort_t* xb     = qkv + (size_t)M * 1152;          // M*384 bf16
  ushort_t* qkvwT  = xb + (size_t)M * 384;            // 1152*384 bf16
  ushort_t* projwT = qkvwT + (size_t)1152 * 384;      // 384*384 bf16

  cvt_x<<<(M * 384 / 8 + 255) / 256, 256, 0, stream>>>(x, xb, M * 384 / 8);
  transpose_k<<<(384 * 1152 + 255) / 256, 256, 0, stream>>>(qkv_w, qkvwT, 384, 1152);
  transpose_k<<<(384 * 384 + 255) / 256, 256, 0, stream>>>(proj_w, projwT, 384, 384);

  // QKV projection: A = xb (bf16), C = qkv (bf16). grid = (M/128)*(N/128), %8==0
  gemm_bt<0><<<(M / 128) * (1152 / 128), 256, 0, stream>>>(
      xb, 384, qkvwT, nullptr, qkv, M, 1152, 384);

  win_attn<<<16 * 64, 256, 0, stream>>>(qkv, qkv, 1152);

  // proj: A = attn out (bf16, aliased in qkv cols 0..383), C = out (f32)
  gemm_bt<1><<<(M / 128) * (384 / 128), 256, 0, stream>>>(
      qkv, 1152, projwT, proj_b, out, M, 384, 384);
}

// Round 4
// 329.614 us; speedup vs baseline: 1.1068x; 1.0378x over previous
//
#include <hip/hip_runtime.h>
#include <stdint.h>

typedef unsigned short ushort_t;
typedef __bf16 bf16x8 __attribute__((ext_vector_type(8)));
typedef float floatx4 __attribute__((ext_vector_type(4)));
typedef float floatx16 __attribute__((ext_vector_type(16)));
typedef unsigned short ushort8 __attribute__((ext_vector_type(8)));

__device__ __forceinline__ ushort_t f2b(float f) {
  union { float f; unsigned u; } v; v.f = f;
  unsigned r = v.u + 0x7fffu + ((v.u >> 16) & 1u);  // RNE
  return (ushort_t)(r >> 16);
}
__device__ __forceinline__ ushort_t b2u(float f) {  // native hw cvt
  union { __bf16 b; ushort_t u; } v; v.b = (__bf16)f; return v.u;
}
__device__ __forceinline__ bf16x8 cvt8(const float* p) {
  floatx4 f0 = *(const floatx4*)p;
  floatx4 f1 = *(const floatx4*)(p + 4);
  union { bf16x8 v; __bf16 e[8]; } u;
#pragma unroll
  for (int j = 0; j < 4; ++j) u.e[j] = (__bf16)f0[j];
#pragma unroll
  for (int j = 0; j < 4; ++j) u.e[4 + j] = (__bf16)f1[j];
  return u.v;
}

// pack two f32 -> one dword of two bf16 (lo = a, hi = b), RNE hw cvt
__device__ __forceinline__ unsigned cvtpk(float a, float b) {
  unsigned r;
  asm("v_cvt_pk_bf16_f32 %0, %1, %2" : "=v"(r) : "v"(a), "v"(b));
  return r;
}
// exchange x.lanes[32..63] <-> y.lanes[0..31]
__device__ __forceinline__ void plswap(unsigned& x, unsigned& y) {
  asm("v_permlane32_swap_b32 %0, %1" : "+v"(x), "+v"(y));
}

// async global->LDS, 16 bytes per lane (wave-uniform LDS base + lane*16)
__device__ __forceinline__ void async16(const ushort_t* g, ushort_t* l) {
  __builtin_amdgcn_global_load_lds(
      (const __attribute__((address_space(1))) void*)g,
      (__attribute__((address_space(3))) void*)l, 16, 0, 0);
}

// -------- x f32 -> bf16, 8 elems/thread --------
__global__ __launch_bounds__(256) void cvt_x(const float* __restrict__ src,
                                             ushort_t* __restrict__ dst, int n8) {
  int i = blockIdx.x * 256 + threadIdx.x;
  if (i < n8) *(bf16x8*)&dst[(size_t)i * 8] = cvt8(src + (size_t)i * 8);
}

// -------- weight transpose + f32->bf16: src[R][Cc] f32 -> dst[Cc][R] bf16 ----
__global__ void transpose_k(const float* __restrict__ src,
                            ushort_t* __restrict__ dst, int R, int Cc) {
  int idx = blockIdx.x * 256 + threadIdx.x;
  if (idx < R * Cc) {
    int r = idx / Cc, c = idx % Cc;
    dst[(size_t)c * R + r] = f2b(src[idx]);
  }
}

// -------- GEMM (round-1 verified): C[M][N] = A[M][K] @ Bt[N][K]^T (+bias) ----
// 128x128 tile, 4 waves, BK=64, XOR-swizzled LDS (both-sides), XCD swizzle.
template <int C_F32>
__global__ __launch_bounds__(256) void gemm_bt(
    const ushort_t* __restrict__ A, int lda,
    const ushort_t* __restrict__ Bt,
    const float* __restrict__ bias, void* __restrict__ C_,
    int M, int N, int K) {
  __shared__ __align__(16) ushort_t As[128 * 64];
  __shared__ __align__(16) ushort_t Bs[128 * 64];
  const int t = threadIdx.x;
  const int nwg = gridDim.x;
  const int per = nwg >> 3;
  const int swz = (blockIdx.x & 7) * per + (blockIdx.x >> 3);
  const int ntn = N >> 7;
  const int m0 = (swz / ntn) << 7;
  const int n0 = (swz % ntn) << 7;
  const int w = t >> 6, lane = t & 63;
  const int wy = (w >> 1) << 6;
  const int wx = (w & 1) << 6;
  const int l15 = lane & 15;
  const int quad = lane >> 4;
  const int quad4 = quad << 2;
  floatx4 acc[4][4] = {};
  const int srow = t >> 3;
  const int sc = (((t & 7) ^ (srow & 7)) << 3);
  const ushort_t* gA = A + (size_t)(m0 + srow) * lda + sc;
  const ushort_t* gB = Bt + (size_t)(n0 + srow) * K + sc;
  for (int k0 = 0; k0 < K; k0 += 64) {
    __syncthreads();
#pragma unroll
    for (int r4 = 0; r4 < 4; ++r4) {
      async16(gA + (size_t)r4 * 32 * lda + k0, &As[r4 * 2048 + t * 8]);
      async16(gB + (size_t)r4 * 32 * K + k0, &Bs[r4 * 2048 + t * 8]);
    }
    __syncthreads();
#pragma unroll
    for (int kk = 0; kk < 2; ++kk) {
      bf16x8 af[4], bfr[4];
#pragma unroll
      for (int i = 0; i < 4; ++i) {
        int row = wy + i * 16 + l15;
        af[i] = *(const bf16x8*)&As[row * 64 + ((((kk << 2) | quad) ^ (row & 7)) << 3)];
      }
#pragma unroll
      for (int j = 0; j < 4; ++j) {
        int row = wx + j * 16 + l15;
        bfr[j] = *(const bf16x8*)&Bs[row * 64 + ((((kk << 2) | quad) ^ (row & 7)) << 3)];
      }
#pragma unroll
      for (int i = 0; i < 4; ++i)
#pragma unroll
        for (int j = 0; j < 4; ++j)
          acc[i][j] = __builtin_amdgcn_mfma_f32_16x16x32_bf16(
              af[i], bfr[j], acc[i][j], 0, 0, 0);
    }
  }
  float bv[4] = {0.f, 0.f, 0.f, 0.f};
  if (bias != nullptr) {
#pragma unroll
    for (int j = 0; j < 4; ++j) bv[j] = bias[n0 + wx + j * 16 + l15];
  }
#pragma unroll
  for (int i = 0; i < 4; ++i) {
#pragma unroll
    for (int r = 0; r < 4; ++r) {
      size_t row = (size_t)(m0 + wy + i * 16 + quad4 + r);
      if (C_F32) {
        float* cp = (float*)C_ + row * N + (n0 + wx + l15);
#pragma unroll
        for (int j = 0; j < 4; ++j) cp[j * 16] = acc[i][j][r] + bv[j];
      } else {
        ushort_t* cp = (ushort_t*)C_ + row * N + (n0 + wx + l15);
#pragma unroll
        for (int j = 0; j < 4; ++j) cp[j * 16] = f2b(acc[i][j][r] + bv[j]);
      }
    }
  }
}

// -------- fused window attention + proj GEMM --------
// QKV: [B*4096][1152] bf16, col = c3*384 + h*32 + d (read-only here).
// Phase 1 (attn, round-3 verified math): 32x32 MFMA, swapped QK^T, in-register
// P via cvt_pk + permlane32_swap. Epilogue writes bf16 attn-out into LDS
// Ao[64][384] with the chunk^(tok&7) XOR swizzle (bank-conflict-free reads).
// Phase 2 (proj): one barrier, then per-wave 64x96 stripe of
// out = Ao @ projwT^T + bias, B-frags read direct from global (L2-resident
// 288 KB shared by all blocks), coalesced f32 stores.
// A window-block holds ALL 12 heads (4 waves x 3), so the block's Ao is the
// complete proj A-panel: eliminates the separate proj kernel + 100 MB of
// HBM round-trip for the attn output.
__global__ __launch_bounds__(256, 2) void attn_proj(
    const ushort_t* __restrict__ QKV, const ushort_t* __restrict__ Bt,
    const float* __restrict__ bias, float* __restrict__ out) {
  __shared__ __align__(16) ushort_t Vt[4][32 * 72];  // [d][64 tokens + pad]
  __shared__ __align__(16) ushort_t Ao[64 * 384];    // swizzled attn out
  const int blk = blockIdx.x;
  const int b = blk >> 6, g = blk & 63;
  const int gy = g >> 3, gx = g & 7;
  const int t = threadIdx.x, w = t >> 6, lane = t & 63;
  const int l31 = lane & 31, bh = lane >> 5;
  const int l15 = lane & 15, quad = lane >> 4, quad4 = quad << 2;
  // token tok (0..63, iy-major) -> global row = bbase + (tok>>3)*64 + (tok&7)
  const size_t bbase = (size_t)b * 4096 + (size_t)(gy * 8) * 64 + gx * 8;
  const float scale = 0.17677669529663687f;  // 1/sqrt(32)

  // ---------------- phase 1: window attention (3 heads per wave) ----------
  for (int hi = 0; hi < 3; ++hi) {
    const int h = w * 3 + hi;
    const size_t hq = (size_t)h * 32;

    // stage V^T into per-wave LDS: Vt[d][tok], stride 72 (2-way/free banks)
    {
      size_t row = bbase + (size_t)(lane >> 3) * 64 + (lane & 7);
      const ushort_t* vp = QKV + row * 1152 + 768 + hq;
#pragma unroll
      for (int i = 0; i < 4; ++i) {
        ushort8 vv = *(const ushort8*)(vp + i * 8);
#pragma unroll
        for (int j = 0; j < 8; ++j) Vt[w][(i * 8 + j) * 72 + lane] = vv[j];
      }
    }

    // Q B-frags (persist): Q[q = qt*32+l31][d = dc*16 + bh*8 .. +7]
    bf16x8 qf[2][2];
#pragma unroll
    for (int qt = 0; qt < 2; ++qt) {
      int tok = qt * 32 + l31;
      size_t row = bbase + (size_t)(tok >> 3) * 64 + (tok & 7);
#pragma unroll
      for (int dc = 0; dc < 2; ++dc)
        qf[qt][dc] = *(const bf16x8*)(QKV + row * 1152 + hq + dc * 16 + bh * 8);
    }

    // S^T = K Q^T: st[kt][qt] lane holds
    // S[q = qt*32+l31][k = kt*32 + (reg&3)+8*(reg>>2)+4*bh]
    floatx16 st[2][2] = {};
#pragma unroll
    for (int kt = 0; kt < 2; ++kt) {
      bf16x8 kf[2];
      int tok = kt * 32 + l31;
      size_t row = bbase + (size_t)(tok >> 3) * 64 + (tok & 7);
#pragma unroll
      for (int dc = 0; dc < 2; ++dc)
        kf[dc] = *(const bf16x8*)(QKV + row * 1152 + 384 + hq + dc * 16 + bh * 8);
#pragma unroll
      for (int qt = 0; qt < 2; ++qt)
#pragma unroll
        for (int dc = 0; dc < 2; ++dc)
          st[kt][qt] = __builtin_amdgcn_mfma_f32_32x32x16_bf16(
              kf[dc], qf[qt][dc], st[kt][qt], 0, 0, 0);
    }

    // softmax: p = exp(s*scale); lane-local partial rowsum + 1 cross-half xchg
    float rs[2] = {0.f, 0.f};
#pragma unroll
    for (int kt = 0; kt < 2; ++kt)
#pragma unroll
      for (int qt = 0; qt < 2; ++qt)
#pragma unroll
        for (int r = 0; r < 16; ++r) {
          float e = __expf(st[kt][qt][r] * scale);
          st[kt][qt][r] = e;
          rs[qt] += e;
        }
#pragma unroll
    for (int qt = 0; qt < 2; ++qt) rs[qt] += __shfl_xor(rs[qt], 32);
    float inv[2] = {1.0f / rs[0], 1.0f / rs[1]};

    // PV: normalized-P A-frags in-register (cvt_pk + permlane swaps)
    floatx16 o[2] = {};
#pragma unroll
    for (int s = 0; s < 4; ++s) {
      const int kt = s >> 1, r1x = (s & 1) << 1;
      bf16x8 vf = *(const bf16x8*)&Vt[w][l31 * 72 + s * 16 + bh * 8];
#pragma unroll
      for (int qt = 0; qt < 2; ++qt) {
        float iv = inv[qt];
        unsigned x0 = cvtpk(st[kt][qt][4 * r1x + 0] * iv, st[kt][qt][4 * r1x + 1] * iv);
        unsigned x1 = cvtpk(st[kt][qt][4 * r1x + 2] * iv, st[kt][qt][4 * r1x + 3] * iv);
        unsigned y0 = cvtpk(st[kt][qt][4 * r1x + 4] * iv, st[kt][qt][4 * r1x + 5] * iv);
        unsigned y1 = cvtpk(st[kt][qt][4 * r1x + 6] * iv, st[kt][qt][4 * r1x + 7] * iv);
        plswap(x0, y0);
        plswap(x1, y1);
        union { unsigned d[4]; bf16x8 v; } pa;
        pa.d[0] = x0; pa.d[1] = x1; pa.d[2] = y0; pa.d[3] = y1;
        o[qt] = __builtin_amdgcn_mfma_f32_32x32x16_bf16(pa.v, vf, o[qt], 0, 0, 0);
      }
    }

    // write attn-out (already normalized P => o is final) to swizzled LDS Ao:
    // elem (tok, k=h*32+l31) at tok*384 + (k&~63) + (((k>>3&7)^(tok&7))<<3) + (k&7)
    const int base64 = (h >> 1) << 6;
    const int cbase = ((h & 1) << 2) | (l31 >> 3);
    const int e7 = l31 & 7;
#pragma unroll
    for (int qt = 0; qt < 2; ++qt)
#pragma unroll
      for (int r = 0; r < 16; ++r) {
        int tok = qt * 32 + (r & 3) + 8 * (r >> 2) + 4 * bh;
        int c = cbase ^ (tok & 7);
        Ao[tok * 384 + base64 + (c << 3) + e7] = b2u(o[qt][r]);
      }
  }

  __syncthreads();  // Ao complete (all waves, all heads)

  // ---------------- phase 2: proj GEMM out = Ao @ Bt^T + bias -------------
  // wave w: rows 0..63, cols [w*96, w*96+96). K = 384, 12 k-steps of 32.
  floatx4 acc[4][6] = {};
  for (int ks = 0; ks < 12; ++ks) {
    bf16x8 af[4];
#pragma unroll
    for (int i = 0; i < 4; ++i) {
      int row = i * 16 + l15;
      int c = (((ks & 1) << 2) | quad) ^ (row & 7);
      af[i] = *(const bf16x8*)&Ao[row * 384 + ((ks >> 1) << 6) + (c << 3)];
    }
    bf16x8 bfr[6];
#pragma unroll
    for (int j = 0; j < 6; ++j) {
      int n = w * 96 + j * 16 + l15;
      bfr[j] = *(const bf16x8*)&Bt[(size_t)n * 384 + ks * 32 + (quad << 3)];
    }
#pragma unroll
    for (int i = 0; i < 4; ++i)
#pragma unroll
      for (int j = 0; j < 6; ++j)
        acc[i][j] = __builtin_amdgcn_mfma_f32_16x16x32_bf16(
            af[i], bfr[j], acc[i][j], 0, 0, 0);
  }

  float bv[6];
#pragma unroll
  for (int j = 0; j < 6; ++j) bv[j] = bias[w * 96 + j * 16 + l15];
#pragma unroll
  for (int i = 0; i < 4; ++i) {
#pragma unroll
    for (int r = 0; r < 4; ++r) {
      int tok = i * 16 + quad4 + r;
      size_t grow = bbase + (size_t)(tok >> 3) * 64 + (tok & 7);
      float* cp = out + grow * 384 + w * 96 + l15;
#pragma unroll
      for (int j = 0; j < 6; ++j) cp[j * 16] = acc[i][j][r] + bv[j];
    }
  }
}

extern "C" void kernel_launch(void* const* d_in, const int* in_sizes, int n_in,
                              void* d_out, int out_size, void* d_ws, size_t ws_size,
                              hipStream_t stream) {
  const float* x      = (const float*)d_in[0];  // [65536][384] f32
  const float* qkv_w  = (const float*)d_in[1];  // [384][1152] f32
  const float* proj_w = (const float*)d_in[2];  // [384][384] f32
  const float* proj_b = (const float*)d_in[3];  // [384] f32
  float* out = (float*)d_out;                   // [65536][384] f32

  const int M = 16 * 4096;  // 65536 tokens
  const size_t need =
      ((size_t)M * 1152 + (size_t)M * 384 + 1152 * 384 + 384 * 384) * 2;
  if (ws_size < need) return;  // diagnostic: finite absmax => ws too small

  ushort_t* qkv    = (ushort_t*)d_ws;                 // M*1152 bf16
  ushort_t* xb     = qkv + (size_t)M * 1152;          // M*384 bf16
  ushort_t* qkvwT  = xb + (size_t)M * 384;            // 1152*384 bf16
  ushort_t* projwT = qkvwT + (size_t)1152 * 384;      // 384*384 bf16

  cvt_x<<<(M * 384 / 8 + 255) / 256, 256, 0, stream>>>(x, xb, M * 384 / 8);
  transpose_k<<<(384 * 1152 + 255) / 256, 256, 0, stream>>>(qkv_w, qkvwT, 384, 1152);
  transpose_k<<<(384 * 384 + 255) / 256, 256, 0, stream>>>(proj_w, projwT, 384, 384);

  // QKV projection: A = xb (bf16), C = qkv (bf16). grid = (M/128)*(N/128), %8==0
  gemm_bt<0><<<(M / 128) * (1152 / 128), 256, 0, stream>>>(
      xb, 384, qkvwT, nullptr, qkv, M, 1152, 384);

  // fused window attention + proj (replaces win_attn + gemm_bt<1>)
  attn_proj<<<16 * 64, 256, 0, stream>>>(qkv, projwT, proj_b, out);
}